// Round 6
// baseline (929.418 us; speedup 1.0000x reference)
//
#include <hip/hip_runtime.h>

// ModulatedConv2d: B=16, C=512->512, 3x3 SAME, per-sample demodulated weights.
// R5: A (weights) moved out of LDS. k_wt writes wt2 in MFMA-fragment order
// ([b][t][icb][otile][kk][lane][8]) so k_conv loads A-frags global->VGPR
// coalesced (L1/L2-resident, 16KB tap-slice shared by 4 waves x 32 blocks).
// LDS holds only sX (28.7KB) -> 3 blocks/CU; 2 __syncthreads per chunk
// (was 18); LDS-read traffic halved (the R1 binder: 184us of ds_read_b128
// throughput on the per-CU LDS pipe). R4 lesson: counted-vmcnt pipelining
// at 2 blocks/CU LOST to plain barriers at 3 blocks/CU -> keep it simple.

typedef __bf16 bf16x8 __attribute__((ext_vector_type(8)));
typedef float f32x4 __attribute__((ext_vector_type(4)));

__device__ __forceinline__ void async16(const void* g, void* s) {
  __builtin_amdgcn_global_load_lds((const __attribute__((address_space(1))) void*)g,
                                   (__attribute__((address_space(3))) void*)s, 16, 0, 0);
}

// style[b][i] = dot(w_embs[b,:], style_W[i,:]) + style_b[i] + 1
__global__ __launch_bounds__(256) void k_style(const float* __restrict__ we,
                                               const float* __restrict__ sW,
                                               const float* __restrict__ sb,
                                               float* __restrict__ style) {
  int lane = threadIdx.x & 63, wid = threadIdx.x >> 6;
  int b = blockIdx.x >> 7;
  int i = ((blockIdx.x & 127) << 2) + wid;
  const float* wer = we + b * 512;
  const float* swr = sW + i * 512;
  float acc = 0.f;
  for (int d = lane; d < 512; d += 64) acc += wer[d] * swr[d];
#pragma unroll
  for (int off = 32; off; off >>= 1) acc += __shfl_xor(acc, off);
  if (lane == 0) style[b * 512 + i] = acc + sb[i] + 1.0f;
}

// wsq[o][i] = sum_k cw[o][i][k]^2
__global__ __launch_bounds__(256) void k_wsq(const float* __restrict__ cw,
                                             float* __restrict__ wsq) {
  int t = blockIdx.x * 256 + threadIdx.x;  // o*512+i
  const float* p = cw + (long)t * 9;
  float s = 0.f;
#pragma unroll
  for (int k = 0; k < 9; ++k) s += p[k] * p[k];
  wsq[t] = s;
}

// rnorm[b][o] = rsqrt(sum_i style[b,i]^2 * wsq[o,i])
__global__ __launch_bounds__(256) void k_rnorm(const float* __restrict__ style,
                                               const float* __restrict__ wsq,
                                               float* __restrict__ rnorm) {
  int lane = threadIdx.x & 63, wid = threadIdx.x >> 6;
  int idx = blockIdx.x * 4 + wid;  // b*512 + o
  int b = idx >> 9, o = idx & 511;
  float acc = 0.f;
  for (int i = lane; i < 512; i += 64) {
    float s = style[(b << 9) + i];
    acc += s * s * wsq[(o << 9) + i];
  }
#pragma unroll
  for (int off = 32; off; off >>= 1) acc += __shfl_xor(acc, off);
  if (lane == 0) rnorm[idx] = rsqrtf(acc);
}

// wt2 fragment layout: flat index f = ((((b*9+t)*8+icb)*32+ot)*2+kk)*64+lane,
// 8 bf16 elems at f*8: elem j = cw[o][ic0+j][t] * style[b][ic0+j] * rnorm[b][o]
// with o = ot*16 + (lane&15), ic0 = icb*64 + kk*32 + (lane>>4)*8.
// A wave's MFMA A-frag load is then base + lane*16 (coalesced 1KB).
__global__ __launch_bounds__(256) void k_wt(const float* __restrict__ cw,
                                            const float* __restrict__ style,
                                            const float* __restrict__ rnorm,
                                            __bf16* __restrict__ wt2) {
  int tid = blockIdx.x * 256 + threadIdx.x;  // < 4,718,592
  int lane = tid & 63;
  int kk = (tid >> 6) & 1;
  int ot = (tid >> 7) & 31;
  int icb = (tid >> 12) & 7;
  int bt = tid >> 15;          // b*9 + t, 0..143
  int b = bt / 9, t = bt - 9 * b;
  int o = (ot << 4) + (lane & 15);
  int ic0 = (icb << 6) + (kk << 5) + ((lane >> 4) << 3);
  float rn = rnorm[(b << 9) + o];
  const float* cwo = cw + ((long)o << 9) * 9 + t;  // cw[o][ic][t], ic stride 9
  const float* stb = style + (b << 9);
  bf16x8 v;
#pragma unroll
  for (int j = 0; j < 8; ++j) {
    int ic = ic0 + j;
    v[j] = (__bf16)(cwo[(long)ic * 9] * stb[ic] * rn);
  }
  *(bf16x8*)(wt2 + (long)tid * 8) = v;
}

// xpad[b][r][c][i] (r,c in [0,66)) = bf16(imgs[b][i][r-1][c-1]), zero border.
__global__ __launch_bounds__(256) void k_xpad(const float* __restrict__ imgs,
                                              __bf16* __restrict__ xpad) {
  int t = blockIdx.x * 256 + threadIdx.x;  // b*4356 + r*66 + c
  if (t >= 16 * 4356) return;
  int b = t / 4356;
  int rc = t - b * 4356;
  int r = rc / 66, c = rc - (rc / 66) * 66;
  __bf16* dst = xpad + (long)t * 512;
  if (r == 0 || r == 65 || c == 0 || c == 65) {
    const f32x4 z = {0.f, 0.f, 0.f, 0.f};
#pragma unroll 4
    for (int j = 0; j < 64; ++j) *(f32x4*)(dst + j * 8) = z;
  } else {
    const float* src = imgs + ((long)b << 21) + ((r - 1) << 6) + (c - 1);
    for (int j = 0; j < 64; ++j) {
      bf16x8 v;
#pragma unroll
      for (int q = 0; q < 8; ++q) v[q] = (__bf16)src[(long)(j * 8 + q) << 12];
      *(bf16x8*)(dst + j * 8) = v;
    }
  }
}

// Conv: block = 128 out-chans x 128 px (4h x 32w), 4 waves (2x2 of 64x64).
// B (X) from LDS (T2-swizzled, conflict-free); A direct global->reg from wt2.
__global__ __launch_bounds__(256, 3) void k_conv(const __bf16* __restrict__ xpad,
                                                 const __bf16* __restrict__ wt2,
                                                 const float* __restrict__ bias,
                                                 float* __restrict__ out) {
  __shared__ __attribute__((aligned(16))) __bf16 sX[224 * 64];  // 204 px used

  const int tid = threadIdx.x;
  const int lane = tid & 63;
  const int wid = tid >> 6;
  const int wr = wid >> 1, wc = wid & 1;
  const int l15 = lane & 15, lq = lane >> 4;

  const int bid = blockIdx.x;
  const int b = bid >> 7;          // 128 blocks / batch
  const int r7 = bid & 127;
  const int o0 = (r7 >> 5) << 7;   // 4 o-tiles of 128
  const int st = r7 & 31;          // 32 spatial tiles
  const int h0 = (st >> 1) << 2;   // 16 h-tiles * 4 rows
  const int w0 = (st & 1) << 5;    // 2 w-tiles * 32 cols

  // X staging: 1792 16B slots; slot s -> px p=s>>3, holds chunk (s&7)^(p&7).
  const __bf16* xg[7];
#pragma unroll
  for (int it = 0; it < 7; ++it) {
    int s = it * 256 + tid;
    int p = s >> 3;
    int pp = (p < 204) ? p : 0;  // pad slots read dummy, never consumed
    int j = (s & 7) ^ (pp & 7);
    int lr = pp / 34, lc = pp - lr * 34;
    xg[it] = xpad + ((long)((b * 66 + h0 + lr) * 66) + (w0 + lc)) * 512 + j * 8;
  }
  // A-frag base for this wave: otile group = o0/16 + wr*4 (+m), per (b,t,icb).
  const int otb = (o0 >> 4) + (wr << 2);

  f32x4 acc[4][4];
  const f32x4 zero4 = {0.f, 0.f, 0.f, 0.f};
#pragma unroll
  for (int m = 0; m < 4; ++m)
#pragma unroll
    for (int n = 0; n < 4; ++n) acc[m][n] = zero4;

  int prn[4], pcn[4];
#pragma unroll
  for (int n = 0; n < 4; ++n) {
    int nn = (wc << 6) + (n << 4) + l15;
    prn[n] = nn >> 5;
    pcn[n] = nn & 31;
  }

  // ---- prologue: stage X(chunk 0) ----
#pragma unroll
  for (int it = 0; it < 7; ++it)
    async16(xg[it], (char*)sX + it * 4096 + (wid << 10));

  for (int icb = 0; icb < 8; ++icb) {
    __syncthreads();  // drains staging (vmcnt 0) + waves aligned; sX ready
#pragma unroll
    for (int t = 0; t < 9; ++t) {
      const int ky = t / 3, kx = t - (t / 3) * 3;
      // A-frag base (elements) for (b, t, icb, this wave's otile block)
      const __bf16* ab =
          wt2 + ((((long)(b * 9 + t) * 8 + icb) * 32 + otb) * 2) * 512 +
          (lane << 3);
#pragma unroll
      for (int kk = 0; kk < 2; ++kk) {
        const int jb = lq + (kk << 2);
        bf16x8 af[4], bfr[4];
#pragma unroll
        for (int m = 0; m < 4; ++m)
          af[m] = *(const bf16x8*)(ab + (((m << 1) + kk) << 9));
#pragma unroll
        for (int n = 0; n < 4; ++n) {
          int p = (prn[n] + ky) * 34 + pcn[n] + kx;
          bfr[n] = *(const bf16x8*)&sX[(p << 6) + ((jb ^ (p & 7)) << 3)];
        }
#pragma unroll
        for (int m = 0; m < 4; ++m)
#pragma unroll
          for (int n = 0; n < 4; ++n)
            acc[m][n] = __builtin_amdgcn_mfma_f32_16x16x32_bf16(af[m], bfr[n],
                                                                acc[m][n], 0, 0, 0);
      }
    }
    if (icb < 7) {
      __syncthreads();  // all waves done reading sX for this chunk
      const int icn = (icb + 1) << 6;
#pragma unroll
      for (int it = 0; it < 7; ++it)
        async16(xg[it] + icn, (char*)sX + it * 4096 + (wid << 10));
    }
  }

  // Epilogue: C/D col=lane&15 (pixel), row=(lane>>4)*4+q (out chan).
  float* outb = out + ((long)b << 21);
#pragma unroll
  for (int m = 0; m < 4; ++m) {
    int ob = o0 + (wr << 6) + (m << 4) + (lq << 2);
#pragma unroll
    for (int n = 0; n < 4; ++n) {
      int h = h0 + prn[n], w = w0 + pcn[n];
#pragma unroll
      for (int q = 0; q < 4; ++q) {
        int o = ob + q;
        outb[((long)o << 12) + (h << 6) + w] = acc[m][n][q] + bias[o];
      }
    }
  }
}

extern "C" void kernel_launch(void* const* d_in, const int* in_sizes, int n_in,
                              void* d_out, int out_size, void* d_ws, size_t ws_size,
                              hipStream_t stream) {
  const float* imgs = (const float*)d_in[0];
  const float* w_embs = (const float*)d_in[1];
  const float* cw = (const float*)d_in[2];
  const float* bias = (const float*)d_in[3];
  const float* style_W = (const float*)d_in[4];
  const float* style_b = (const float*)d_in[5];
  float* out = (float*)d_out;

  char* ws = (char*)d_ws;
  float* style = (float*)(ws);                          // 32 KB
  float* rnorm = (float*)(ws + (32 << 10));             // 32 KB
  float* wsq = (float*)(ws + (64 << 10));               // 1 MB
  __bf16* wt2 = (__bf16*)(ws + (64 << 10) + (1 << 20));  // 75,497,472 B
  __bf16* xpad = (__bf16*)(ws + (64 << 10) + (1 << 20) + 75497472);  // 71,368,704 B
  size_t need = (size_t)(64 << 10) + (1 << 20) + 75497472ull + 71368704ull;
  if (ws_size < need) return;  // leaves d_out poisoned -> visible failure mode

  k_style<<<2048, 256, 0, stream>>>(w_embs, style_W, style_b, style);
  k_wsq<<<1024, 256, 0, stream>>>(cw, wsq);
  k_rnorm<<<2048, 256, 0, stream>>>(style, wsq, rnorm);
  k_wt<<<18432, 256, 0, stream>>>(cw, style, rnorm, wt2);
  k_xpad<<<273, 256, 0, stream>>>(imgs, xpad);
  k_conv<<<2048, 256, 0, stream>>>(xpad, wt2, bias, out);
}

// Round 8
// 383.695 us; speedup vs baseline: 2.4223x; 2.4223x over previous
//
#include <hip/hip_runtime.h>

// ModulatedConv2d: B=16, C=512->512, 3x3 SAME, per-sample demodulated weights.
// R7 = R6 with the A-slab staging address FIXED: source stride is 4 sub-loads
// of 16384 elems (32 o-rows) per tap, then jump +262144 to the next ky tap
// (R6 wrongly used uniform it*16384 -> ky=1,2 slabs got wrong weights,
// absmax 6.5). Phase = (chunk,kx): stage 3-tap A-slab (48KB, kx-major order
// from k_wt); per kk read bfr[4 rows][2 halves] once, sweep ky=0..2.
// LDS reads -17% vs R2-311us, barriers 144->48. LDS 77.8KB -> 2 blocks/CU.

typedef __bf16 bf16x8 __attribute__((ext_vector_type(8)));
typedef float f32x4 __attribute__((ext_vector_type(4)));

__device__ __forceinline__ void async16(const void* g, void* s) {
  __builtin_amdgcn_global_load_lds((const __attribute__((address_space(1))) void*)g,
                                   (__attribute__((address_space(3))) void*)s, 16, 0, 0);
}

// style[b][i] = dot(w_embs[b,:], style_W[i,:]) + style_b[i] + 1
__global__ __launch_bounds__(256) void k_style(const float* __restrict__ we,
                                               const float* __restrict__ sW,
                                               const float* __restrict__ sb,
                                               float* __restrict__ style) {
  int lane = threadIdx.x & 63, wid = threadIdx.x >> 6;
  int b = blockIdx.x >> 7;
  int i = ((blockIdx.x & 127) << 2) + wid;
  const float* wer = we + b * 512;
  const float* swr = sW + i * 512;
  float acc = 0.f;
  for (int d = lane; d < 512; d += 64) acc += wer[d] * swr[d];
#pragma unroll
  for (int off = 32; off; off >>= 1) acc += __shfl_xor(acc, off);
  if (lane == 0) style[b * 512 + i] = acc + sb[i] + 1.0f;
}

// wsq[o][i] = sum_k cw[o][i][k]^2
__global__ __launch_bounds__(256) void k_wsq(const float* __restrict__ cw,
                                             float* __restrict__ wsq) {
  int t = blockIdx.x * 256 + threadIdx.x;  // o*512+i
  const float* p = cw + (long)t * 9;
  float s = 0.f;
#pragma unroll
  for (int k = 0; k < 9; ++k) s += p[k] * p[k];
  wsq[t] = s;
}

// rnorm[b][o] = rsqrt(sum_i style[b,i]^2 * wsq[o,i])
__global__ __launch_bounds__(256) void k_rnorm(const float* __restrict__ style,
                                               const float* __restrict__ wsq,
                                               float* __restrict__ rnorm) {
  int lane = threadIdx.x & 63, wid = threadIdx.x >> 6;
  int idx = blockIdx.x * 4 + wid;  // b*512 + o
  int b = idx >> 9, o = idx & 511;
  float acc = 0.f;
  for (int i = lane; i < 512; i += 64) {
    float s = style[(b << 9) + i];
    acc += s * s * wsq[(o << 9) + i];
  }
#pragma unroll
  for (int off = 32; off; off >>= 1) acc += __shfl_xor(acc, off);
  if (lane == 0) rnorm[idx] = rsqrtf(acc);
}

// wt[b][t'][o][i], t' = kx*3 + ky (kx-MAJOR so a (ky=0..2,kx) slab is
// contiguous): value = cw[o][i][ky*3+kx] * style[b][i] * rnorm[b][o].
__global__ __launch_bounds__(256) void k_wt(const float* __restrict__ cw,
                                            const float* __restrict__ style,
                                            const float* __restrict__ rnorm,
                                            __bf16* __restrict__ wt) {
  int t = blockIdx.x * 256 + threadIdx.x;  // b*262144 + o*512 + i
  int b = t >> 18;
  int oi = t & 262143;
  int o = oi >> 9, i = oi & 511;
  float sc = style[(b << 9) + i] * rnorm[(b << 9) + o];
  const float* p = cw + (long)oi * 9;
#pragma unroll
  for (int k = 0; k < 9; ++k) {  // k = ky*3+kx  ->  t' = kx*3+ky
    int tp = (k % 3) * 3 + k / 3;
    wt[((long)(b * 9 + tp) << 18) + ((long)o << 9) + i] = (__bf16)(p[k] * sc);
  }
}

// xpad[b][r][c][i] (r,c in [0,66)) = bf16(imgs[b][i][r-1][c-1]), zero border.
__global__ __launch_bounds__(256) void k_xpad(const float* __restrict__ imgs,
                                              __bf16* __restrict__ xpad) {
  int t = blockIdx.x * 256 + threadIdx.x;  // b*4356 + r*66 + c
  if (t >= 16 * 4356) return;
  int b = t / 4356;
  int rc = t - b * 4356;
  int r = rc / 66, c = rc - (rc / 66) * 66;
  __bf16* dst = xpad + (long)t * 512;
  if (r == 0 || r == 65 || c == 0 || c == 65) {
    const f32x4 z = {0.f, 0.f, 0.f, 0.f};
#pragma unroll 4
    for (int j = 0; j < 64; ++j) *(f32x4*)(dst + j * 8) = z;
  } else {
    const float* src = imgs + ((long)b << 21) + ((r - 1) << 6) + (c - 1);
    for (int j = 0; j < 64; ++j) {
      bf16x8 v;
#pragma unroll
      for (int q = 0; q < 8; ++q) v[q] = (__bf16)src[(long)(j * 8 + q) << 12];
      *(bf16x8*)(dst + j * 8) = v;
    }
  }
}

// Conv: block = 128 out-chans x 128 px (4h x 32w), 4 waves (2x2 of 64x64).
// Phase = (chunk ic, kx): stage 3-tap A-slab (48KB) [+ X at kx==0]; compute
// 2kk x { bfr[4][2] read once, then ky=0..2 with af[4] } = 96 MFMA/phase.
__global__ __launch_bounds__(256, 2) void k_conv(const __bf16* __restrict__ xpad,
                                                 const __bf16* __restrict__ wt,
                                                 const float* __restrict__ bias,
                                                 float* __restrict__ out) {
  __shared__ __attribute__((aligned(16))) __bf16 sX[224 * 64];   // 204 px used
  __shared__ __attribute__((aligned(16))) __bf16 sA3[3 * 8192];  // 3-tap slab

  const int tid = threadIdx.x;
  const int lane = tid & 63;
  const int wid = tid >> 6;
  const int wr = wid >> 1, wc = wid & 1;
  const int l15 = lane & 15, lq = lane >> 4, l7 = lane & 7;

  const int bid = blockIdx.x;
  const int b = bid >> 7;          // 128 blocks / batch
  const int r7 = bid & 127;
  const int o0 = (r7 >> 5) << 7;   // 4 o-tiles of 128
  const int st = r7 & 31;          // 32 spatial tiles
  const int h0 = (st >> 1) << 2;   // 16 h-tiles * 4 rows
  const int w0 = (st & 1) << 5;    // 2 w-tiles * 32 cols

  // X staging: 1792 16B slots; slot s -> px p=s>>3, holds chunk (s&7)^(p&7).
  const __bf16* xg[7];
#pragma unroll
  for (int it = 0; it < 7; ++it) {
    int s = it * 256 + tid;
    int p = s >> 3;
    int pp = (p < 204) ? p : 0;  // pad slots read dummy, never consumed
    int j = (s & 7) ^ (pp & 7);
    int lr = pp / 34, lc = pp - lr * 34;
    xg[it] = xpad + ((long)((b * 66 + h0 + lr) * 66) + (w0 + lc)) * 512 + j * 8;
  }
  // A staging source offset (elements), pre-swizzled. Within a tap: 4
  // sub-loads of 16384 elems (32 o-rows each); tap-to-tap: +262144.
  int aoff0;
  {
    int row = tid >> 3;
    int j = (tid & 7) ^ (row & 7);
    aoff0 = ((o0 + row) << 9) + (j << 3);
  }
  const __bf16* wtb = wt + (long)b * 2359296;

  f32x4 acc[4][4];
  const f32x4 zero4 = {0.f, 0.f, 0.f, 0.f};
#pragma unroll
  for (int m = 0; m < 4; ++m)
#pragma unroll
    for (int n = 0; n < 4; ++n) acc[m][n] = zero4;

  const int arowb = ((wr << 6) + l15) << 6;
  const int rbase = wc << 1;  // wave's first halo row

  bool first = true;
  for (int icb = 0; icb < 8; ++icb) {
    const int ic = icb << 6;
#pragma unroll
    for (int kx = 0; kx < 3; ++kx) {
      if (!first) __syncthreads();  // prior compute done; safe to overwrite
      first = false;
      if (kx == 0) {
#pragma unroll
        for (int it = 0; it < 7; ++it)
          async16(xg[it] + ic, (char*)sX + it * 4096 + (wid << 10));
      }
      {
        const __bf16* wa = wtb + kx * 3 * 262144 + ic + aoff0;
#pragma unroll
        for (int it = 0; it < 12; ++it)
          async16(wa + (it >> 2) * 262144 + (it & 3) * 16384,
                  (char*)sA3 + it * 4096 + (wid << 10));
      }
      __syncthreads();  // compiler drains vmcnt(0) before s_barrier
#pragma unroll
      for (int kk = 0; kk < 2; ++kk) {
        const int jb = lq + (kk << 2);
        const int jA = (jb ^ l7) << 3;
        bf16x8 bfr[4][2];
#pragma unroll
        for (int r = 0; r < 4; ++r)
#pragma unroll
          for (int c = 0; c < 2; ++c) {
            int p = (rbase + r) * 34 + (c << 4) + l15 + kx;
            bfr[r][c] = *(const bf16x8*)&sX[(p << 6) + ((jb ^ (p & 7)) << 3)];
          }
#pragma unroll
        for (int ky = 0; ky < 3; ++ky) {
          const __bf16* sAb = sA3 + ky * 8192;
          bf16x8 af[4];
#pragma unroll
          for (int m = 0; m < 4; ++m)
            af[m] = *(const bf16x8*)&sAb[arowb + (m << 10) + jA];
#pragma unroll
          for (int m = 0; m < 4; ++m)
#pragma unroll
            for (int q = 0; q < 2; ++q)
#pragma unroll
              for (int c = 0; c < 2; ++c)
                acc[m][(q << 1) + c] = __builtin_amdgcn_mfma_f32_16x16x32_bf16(
                    af[m], bfr[q + ky][c], acc[m][(q << 1) + c], 0, 0, 0);
        }
      }
    }
  }

  // Epilogue: C/D col=lane&15 (pixel), row=(lane>>4)*4+q (out chan).
  // n = q*2 + c: pixel id nn = wc*64 + n*16 + l15 (row nn>>5, col nn&31).
  float* outb = out + ((long)b << 21);
#pragma unroll
  for (int m = 0; m < 4; ++m) {
    int ob = o0 + (wr << 6) + (m << 4) + (lq << 2);
#pragma unroll
    for (int n = 0; n < 4; ++n) {
      int nn = (wc << 6) + (n << 4) + l15;
      int h = h0 + (nn >> 5), w = w0 + (nn & 31);
#pragma unroll
      for (int q = 0; q < 4; ++q) {
        int o = ob + q;
        outb[((long)o << 12) + (h << 6) + w] = acc[m][n][q] + bias[o];
      }
    }
  }
}

extern "C" void kernel_launch(void* const* d_in, const int* in_sizes, int n_in,
                              void* d_out, int out_size, void* d_ws, size_t ws_size,
                              hipStream_t stream) {
  const float* imgs = (const float*)d_in[0];
  const float* w_embs = (const float*)d_in[1];
  const float* cw = (const float*)d_in[2];
  const float* bias = (const float*)d_in[3];
  const float* style_W = (const float*)d_in[4];
  const float* style_b = (const float*)d_in[5];
  float* out = (float*)d_out;

  char* ws = (char*)d_ws;
  float* style = (float*)(ws);                          // 32 KB
  float* rnorm = (float*)(ws + (32 << 10));             // 32 KB
  float* wsq = (float*)(ws + (64 << 10));               // 1 MB
  __bf16* wt = (__bf16*)(ws + (64 << 10) + (1 << 20));  // 75,497,472 B
  __bf16* xpad = (__bf16*)(ws + (64 << 10) + (1 << 20) + 75497472);  // 71,368,704 B
  size_t need = (size_t)(64 << 10) + (1 << 20) + 75497472ull + 71368704ull;
  if (ws_size < need) return;  // leaves d_out poisoned -> visible failure mode

  k_style<<<2048, 256, 0, stream>>>(w_embs, style_W, style_b, style);
  k_wsq<<<1024, 256, 0, stream>>>(cw, wsq);
  k_rnorm<<<2048, 256, 0, stream>>>(style, wsq, rnorm);
  k_wt<<<16384, 256, 0, stream>>>(cw, style, rnorm, wt);
  k_xpad<<<273, 256, 0, stream>>>(imgs, xpad);
  k_conv<<<2048, 256, 0, stream>>>(xpad, wt, bias, out);
}